// Round 12
// baseline (502.748 us; speedup 1.0000x reference)
//
#include <hip/hip_runtime.h>

typedef unsigned short u16;
typedef unsigned int   u32;
typedef __attribute__((ext_vector_type(8))) short  short8;
typedef __attribute__((ext_vector_type(4))) float  f32x4;
typedef __attribute__((ext_vector_type(2))) float  f32x2;
typedef __attribute__((ext_vector_type(2))) unsigned int u32v2;
typedef __attribute__((ext_vector_type(4))) unsigned int u32v4;

#define NN 50000
#define NE 800000

__device__ __forceinline__ float bf2f(u16 b) { return __uint_as_float(((u32)b) << 16); }
__device__ __forceinline__ float bflo(u32 p) { return __uint_as_float(p << 16); }
__device__ __forceinline__ float bfhi(u32 p) { return __uint_as_float(p & 0xffff0000u); }
__device__ __forceinline__ u16 f2bf(float f) {
    u32 u = __float_as_uint(f);
    u32 r = u + 0x7fffu + ((u >> 16) & 1u);
    return (u16)(r >> 16);
}
// leaky-relu + clamped exp (clamp is identity for this data's logit range)
__device__ __forceinline__ float lexp(float v) {
    v = v > 0.f ? v : 0.2f * v;
    return __expf(fminf(v, 60.f));
}

// ---------------------------------------------------------------------------
// dtype detection: flag 0=bf16, 1=fp32, 2=all-zero
// ---------------------------------------------------------------------------
struct DetectArgs { const u32* p[13]; int nw[13]; };

__global__ void k_detect(DetectArgs a, int* flags) {
    int t = threadIdx.x;
    if (t >= 13) return;
    const u32* x = a.p[t];
    int n = a.nw[t];
    int hits = 0, nz = 0;
    for (int i = 0; i < n; ++i) {
        u32 w = x[i];
        if (!w) continue;
        ++nz;
        u32 e = (w >> 7) & 0xffu;
        if (e >= 100 && e <= 150) ++hits;
    }
    flags[t] = (nz == 0) ? 2 : ((hits * 2 >= nz) ? 0 : 1);
}

// convert ONLY the 9 small attention params (al/ar/b x 3 layers) to fp32.
struct ConvArgs { const void* s[9]; float* d[9]; int n[9]; int fi[9]; };

__global__ void k_convert(ConvArgs a, const int* __restrict__ flags) {
    int j = blockIdx.y;
    int i = blockIdx.x * 256 + threadIdx.x;
    if (i >= a.n[j]) return;
    int fl = flags[a.fi[j]];
    float v = 0.f;
    if (fl == 1) v = ((const float*)a.s[j])[i];
    else if (fl == 0) v = bf2f(((const u16*)a.s[j])[i]);
    a.d[j][i] = v;
}

// pack W[K=256][N] into MFMA B-fragment order:
// chunk id = (nt*8 + kt)*64 + L holds 8 bf16: W[kt*32 + (L>>4)*8 + j][nt*16 + (L&15)]
__global__ void k_wpack(const void* __restrict__ Wsrc, const int* __restrict__ flags,
                        int fidx, int N, u16* __restrict__ Wp, int nchunks) {
    int id = blockIdx.x * 256 + threadIdx.x;
    if (id >= nchunks) return;
    int L = id & 63, kt = (id >> 6) & 7, nt = id >> 9;
    int col = nt * 16 + (L & 15);
    int krow = kt * 32 + ((L >> 4) & 3) * 8;
    bool isf32 = (flags[fidx] == 1);
#pragma unroll
    for (int j = 0; j < 8; ++j) {
        int s = (krow + j) * N + col;
        Wp[id * 8 + j] = isf32 ? f2bf(((const float*)Wsrc)[s]) : ((const u16*)Wsrc)[s];
    }
}

// ---------------------------------------------------------------------------
// CSR build (graph static across layers) — 3-phase multi-block scan
// ---------------------------------------------------------------------------
__global__ void k_hist(const int* __restrict__ dst, int* __restrict__ deg, int E) {
    int e = blockIdx.x * 256 + threadIdx.x;
    if (e < E) atomicAdd(&deg[dst[e]], 1);
}

__global__ __launch_bounds__(256) void k_scan_partial(const int* __restrict__ deg,
                                                      int* __restrict__ bsum, int n) {
    __shared__ int red[256];
    int t = threadIdx.x;
    int i = blockIdx.x * 256 + t;
    red[t] = (i < n) ? deg[i] : 0;
    __syncthreads();
    for (int ofs = 128; ofs > 0; ofs >>= 1) {
        if (t < ofs) red[t] += red[t + ofs];
        __syncthreads();
    }
    if (t == 0) bsum[blockIdx.x] = red[0];
}

__global__ __launch_bounds__(256) void k_scan_bsum(int* __restrict__ bsum, int nb) {
    __shared__ int s[256];
    int t = threadIdx.x;
    int v = (t < nb) ? bsum[t] : 0;
    s[t] = v;
    __syncthreads();
    for (int ofs = 1; ofs < 256; ofs <<= 1) {
        int x = (t >= ofs) ? s[t - ofs] : 0;
        __syncthreads();
        s[t] += x;
        __syncthreads();
    }
    if (t < nb) bsum[t] = s[t] - v;   // exclusive
}

__global__ __launch_bounds__(256) void k_scan_final(const int* __restrict__ deg,
                                                    const int* __restrict__ bsum,
                                                    int* __restrict__ rowptr,
                                                    int* __restrict__ cursor, int n) {
    __shared__ int s[256];
    int t = threadIdx.x;
    int i = blockIdx.x * 256 + t;
    int v = (i < n) ? deg[i] : 0;
    s[t] = v;
    __syncthreads();
    for (int ofs = 1; ofs < 256; ofs <<= 1) {
        int x = (t >= ofs) ? s[t - ofs] : 0;
        __syncthreads();
        s[t] += x;
        __syncthreads();
    }
    int excl = bsum[blockIdx.x] + s[t] - v;
    if (i < n) {
        rowptr[i] = excl;
        cursor[i] = excl;
        if (i == n - 1) rowptr[n] = excl + v;
    }
}

__global__ void k_scatter(const int* __restrict__ src, const int* __restrict__ dst,
                          int* __restrict__ cursor, int* __restrict__ csr_src, int E) {
    int e = blockIdx.x * 256 + threadIdx.x;
    if (e >= E) return;
    int p = atomicAdd(&cursor[dst[e]], 1);
    csr_src[p] = src[e];
}

// ---------------------------------------------------------------------------
// MFMA GEMM: [nrows,256] x Wp(packed bf16) -> bf16 OUT [nrows,256]
// X read per runtime dtype flag (nullptr flag => bf16 buffer). fp32 path
// converts during LDS staging (same f2bf rounding as the old xprep pass).
// ---------------------------------------------------------------------------
__global__ __launch_bounds__(256) void k_gemm_mfma(const void* __restrict__ Xv,
                                                   const int* __restrict__ xflag,
                                                   const u16* __restrict__ Wp,
                                                   u16* __restrict__ OUT, int nrows) {
    __shared__ u16 As[64 * 256];   // 32 KB
    const int t = threadIdx.x;
    const int w = t >> 6, L = t & 63;
    const int quad = (L >> 4) & 3;
    const int r0 = blockIdx.x * 64;
    const int nb = blockIdx.y * 8;
    const bool xf32 = (xflag != nullptr) && (*xflag == 1);

    short8* Asv = (short8*)As;
    short8 zero = {0, 0, 0, 0, 0, 0, 0, 0};
#pragma unroll
    for (int i = 0; i < 8; ++i) {
        int g = i * 256 + t;
        int row = g >> 5, cc = g & 31;
        int r = r0 + row;
        short8 val = zero;
        if (r < nrows) {
            if (xf32) {
                const f32x4* Xf4 = (const f32x4*)Xv;
                f32x4 lo = Xf4[(size_t)r * 64 + cc * 2];
                f32x4 hi = Xf4[(size_t)r * 64 + cc * 2 + 1];
                val[0] = (short)f2bf(lo[0]); val[1] = (short)f2bf(lo[1]);
                val[2] = (short)f2bf(lo[2]); val[3] = (short)f2bf(lo[3]);
                val[4] = (short)f2bf(hi[0]); val[5] = (short)f2bf(hi[1]);
                val[6] = (short)f2bf(hi[2]); val[7] = (short)f2bf(hi[3]);
            } else {
                val = ((const short8*)Xv)[(size_t)r * 32 + cc];
            }
        }
        Asv[cc * 64 + row] = val;
    }

    const short8* Wv = (const short8*)Wp;
    short8 bf[2][8];
#pragma unroll
    for (int jn = 0; jn < 2; ++jn) {
        int nt = nb + w + jn * 4;
#pragma unroll
        for (int kt = 0; kt < 8; ++kt) bf[jn][kt] = Wv[(nt * 8 + kt) * 64 + L];
    }
    __syncthreads();

    f32x4 acc[4][2];
#pragma unroll
    for (int mi = 0; mi < 4; ++mi)
#pragma unroll
        for (int jn = 0; jn < 2; ++jn) acc[mi][jn] = (f32x4){0.f, 0.f, 0.f, 0.f};

#pragma unroll
    for (int kt = 0; kt < 8; ++kt) {
#pragma unroll
        for (int mi = 0; mi < 4; ++mi) {
            short8 af = Asv[(kt * 4 + quad) * 64 + mi * 16 + (L & 15)];
            acc[mi][0] = __builtin_amdgcn_mfma_f32_16x16x32_bf16(af, bf[0][kt], acc[mi][0], 0, 0, 0);
            acc[mi][1] = __builtin_amdgcn_mfma_f32_16x16x32_bf16(af, bf[1][kt], acc[mi][1], 0, 0, 0);
        }
    }

    const int colbase = blockIdx.y * 128;
#pragma unroll
    for (int mi = 0; mi < 4; ++mi) {
        int rb = r0 + mi * 16 + quad * 4;
#pragma unroll
        for (int jn = 0; jn < 2; ++jn) {
            int c = colbase + (w + jn * 4) * 16 + (L & 15);
#pragma unroll
            for (int reg = 0; reg < 4; ++reg) {
                int r = rb + reg;
                if (r < nrows) OUT[(size_t)r * 256 + c] = f2bf(acc[mi][jn][reg]);
            }
        }
    }
}

// MFMA GEMM layer 2: [nrows,256](bf16) x Wp2 -> bf16 [nrows,32]. BM=128, BN=32.
__global__ __launch_bounds__(256) void k_gemm_mfma32(const u16* __restrict__ Xb,
                                                     const u16* __restrict__ Wp,
                                                     u16* __restrict__ OUT, int nrows) {
    __shared__ u16 As[128 * 256];  // 64 KB
    const int t = threadIdx.x;
    const int w = t >> 6, L = t & 63;
    const int quad = (L >> 4) & 3;
    const int r0 = blockIdx.x * 128;
    const int mh = (w >> 1) * 64, nt = w & 1;

    const short8* Xv = (const short8*)Xb;
    short8* Asv = (short8*)As;
    short8 zero = {0, 0, 0, 0, 0, 0, 0, 0};
#pragma unroll
    for (int i = 0; i < 16; ++i) {
        int g = i * 256 + t;
        int row = g >> 5, cc = g & 31;
        int r = r0 + row;
        Asv[cc * 128 + row] = (r < nrows) ? Xv[(size_t)r * 32 + cc] : zero;
    }

    const short8* Wv = (const short8*)Wp;
    short8 bf[8];
#pragma unroll
    for (int kt = 0; kt < 8; ++kt) bf[kt] = Wv[(nt * 8 + kt) * 64 + L];
    __syncthreads();

    f32x4 acc[4];
#pragma unroll
    for (int mi = 0; mi < 4; ++mi) acc[mi] = (f32x4){0.f, 0.f, 0.f, 0.f};

#pragma unroll
    for (int kt = 0; kt < 8; ++kt) {
#pragma unroll
        for (int mi = 0; mi < 4; ++mi) {
            short8 af = Asv[(kt * 4 + quad) * 128 + mh + mi * 16 + (L & 15)];
            acc[mi] = __builtin_amdgcn_mfma_f32_16x16x32_bf16(af, bf[kt], acc[mi], 0, 0, 0);
        }
    }

#pragma unroll
    for (int mi = 0; mi < 4; ++mi) {
        int rb = r0 + mh + mi * 16 + quad * 4;
        int c = nt * 16 + (L & 15);
#pragma unroll
        for (int reg = 0; reg < 4; ++reg) {
            int r = rb + reg;
            if (r < nrows) OUT[(size_t)r * 32 + c] = f2bf(acc[mi][reg]);
        }
    }
}

// attention logit dots (feat bf16)
__global__ void k_elr8(const u16* __restrict__ featb, const float* __restrict__ al,
                       const float* __restrict__ ar, float* __restrict__ el,
                       float* __restrict__ er, int n) {
    int idx = blockIdx.x * 256 + threadIdx.x;
    if (idx >= n * 8) return;
    int node = idx >> 3, h = idx & 7;
    const u32* fu = (const u32*)featb + (size_t)node * 128 + h * 16;
    const float* A = al + h * 32;
    const float* B = ar + h * 32;
    float sl = 0.f, sr = 0.f;
#pragma unroll
    for (int j = 0; j < 16; ++j) {
        u32 w = fu[j];
        float f0 = bflo(w), f1 = bfhi(w);
        sl += f0 * A[2 * j] + f1 * A[2 * j + 1];
        sr += f0 * B[2 * j] + f1 * B[2 * j + 1];
    }
    el[idx] = sl;
    er[idx] = sr;
}

__global__ void k_elr1(const u16* __restrict__ featb, const float* __restrict__ al,
                       const float* __restrict__ ar, float* __restrict__ el,
                       float* __restrict__ er, int n) {
    int node = blockIdx.x * 256 + threadIdx.x;
    if (node >= n) return;
    const u32* fu = (const u32*)featb + (size_t)node * 16;
    float sl = 0.f, sr = 0.f;
#pragma unroll
    for (int j = 0; j < 16; ++j) {
        u32 w = fu[j];
        float f0 = bflo(w), f1 = bfhi(w);
        sl += f0 * al[2 * j] + f1 * al[2 * j + 1];
        sr += f0 * ar[2 * j] + f1 * ar[2 * j + 1];
    }
    el[node] = sl;
    er[node] = sr;
}

// ---------------------------------------------------------------------------
// fused softmax+gather: TWO NODES PER WAVE (32 lanes x dwordx4 = 8 cols/lane).
// Each wave instruction advances 2 edges. Degree divergence between the pair
// handled by predication (clamped index, ev=0 for finished lanes).
// ---------------------------------------------------------------------------
__global__ __launch_bounds__(256) void k_gather8(const int* __restrict__ rowptr,
                                                 const int* __restrict__ csr_src,
                                                 const float* __restrict__ el,
                                                 const float* __restrict__ er,
                                                 const u32v4* __restrict__ featb4,
                                                 const float* __restrict__ bias,
                                                 u32v4* __restrict__ xout4, int E) {
    int t = threadIdx.x;
    int wave = t >> 6, lane = t & 63;
    int half = lane >> 5, li = lane & 31;  // 32 lanes per node
    int d = blockIdx.x * 8 + wave * 2 + half;
    int q = li;               // owns cols 8q..8q+7
    int h = q >> 2;           // head 0..7
    int b = rowptr[d], e = rowptr[d + 1];
    int deg = e - b;
    int md = max(deg, __shfl_xor(deg, 32, 64));  // pair-max degree
    float erd = er[d * 8 + h];
    float a0 = 0.f, a1 = 0.f, a2 = 0.f, a3 = 0.f;
    float a4 = 0.f, a5 = 0.f, a6 = 0.f, a7 = 0.f, ssum = 0.f;
    for (int it = 0; it < md; it += 4) {
#pragma unroll
        for (int k = 0; k < 4; ++k) {
            int p = b + it + k;
            bool act = p < e;
            int pc = min(p, E - 1);
            int s = csr_src[pc];
            float ev = lexp(el[s * 8 + h] + erd);
            ev = act ? ev : 0.f;
            u32v4 w = featb4[(size_t)s * 32 + q];
            a0 += bflo(w.x) * ev; a1 += bfhi(w.x) * ev;
            a2 += bflo(w.y) * ev; a3 += bfhi(w.y) * ev;
            a4 += bflo(w.z) * ev; a5 += bfhi(w.z) * ev;
            a6 += bflo(w.w) * ev; a7 += bfhi(w.w) * ev;
            ssum += ev;
        }
    }
    float rd = 1.f / (ssum + 1e-9f);
    const float4 bb0 = *(const float4*)&bias[8 * q];
    const float4 bb1 = *(const float4*)&bias[8 * q + 4];
    float v0 = a0 * rd + bb0.x, v1 = a1 * rd + bb0.y;
    float v2 = a2 * rd + bb0.z, v3 = a3 * rd + bb0.w;
    float v4 = a4 * rd + bb1.x, v5 = a5 * rd + bb1.y;
    float v6 = a6 * rd + bb1.z, v7 = a7 * rd + bb1.w;
    v0 = v0 > 0.f ? v0 : expm1f(v0);
    v1 = v1 > 0.f ? v1 : expm1f(v1);
    v2 = v2 > 0.f ? v2 : expm1f(v2);
    v3 = v3 > 0.f ? v3 : expm1f(v3);
    v4 = v4 > 0.f ? v4 : expm1f(v4);
    v5 = v5 > 0.f ? v5 : expm1f(v5);
    v6 = v6 > 0.f ? v6 : expm1f(v6);
    v7 = v7 > 0.f ? v7 : expm1f(v7);
    u32v4 o;
    o.x = (u32)f2bf(v0) | ((u32)f2bf(v1) << 16);
    o.y = (u32)f2bf(v2) | ((u32)f2bf(v3) << 16);
    o.z = (u32)f2bf(v4) | ((u32)f2bf(v5) << 16);
    o.w = (u32)f2bf(v6) | ((u32)f2bf(v7) << 16);
    xout4[(size_t)d * 32 + q] = o;
}

// layer-2 fused gather: 16 lanes/node x u32 (2 cols/lane), 4 nodes/wave.
__global__ __launch_bounds__(256) void k_gather1(const int* __restrict__ rowptr,
                                                 const int* __restrict__ csr_src,
                                                 const float* __restrict__ el,
                                                 const float* __restrict__ er,
                                                 const u32* __restrict__ featb2,
                                                 const float* __restrict__ bias,
                                                 void* __restrict__ out,
                                                 const int* __restrict__ flag, int n) {
    int t = threadIdx.x;
    int d = blockIdx.x * 16 + (t >> 4);
    int q = t & 15;           // owns cols 2q, 2q+1
    if (d >= n) return;
    int b = rowptr[d], e = rowptr[d + 1];
    float erd = er[d];
    float a0 = 0.f, a1 = 0.f, ssum = 0.f;
    int p = b;
    for (; p + 4 <= e; p += 4) {
        int s0 = csr_src[p], s1 = csr_src[p + 1], s2 = csr_src[p + 2], s3 = csr_src[p + 3];
        float e0 = lexp(el[s0] + erd);
        float e1 = lexp(el[s1] + erd);
        float e2 = lexp(el[s2] + erd);
        float e3 = lexp(el[s3] + erd);
        u32 w0 = featb2[(size_t)s0 * 16 + q];
        u32 w1 = featb2[(size_t)s1 * 16 + q];
        u32 w2 = featb2[(size_t)s2 * 16 + q];
        u32 w3 = featb2[(size_t)s3 * 16 + q];
        a0 += bflo(w0) * e0; a1 += bfhi(w0) * e0;
        a0 += bflo(w1) * e1; a1 += bfhi(w1) * e1;
        a0 += bflo(w2) * e2; a1 += bfhi(w2) * e2;
        a0 += bflo(w3) * e3; a1 += bfhi(w3) * e3;
        ssum += (e0 + e1) + (e2 + e3);
    }
    for (; p < e; ++p) {
        int s = csr_src[p];
        float ev = lexp(el[s] + erd);
        u32 w = featb2[(size_t)s * 16 + q];
        a0 += bflo(w) * ev;
        a1 += bfhi(w) * ev;
        ssum += ev;
    }
    float rd = 1.f / (ssum + 1e-9f);
    float v0 = a0 * rd + bias[2 * q];
    float v1 = a1 * rd + bias[2 * q + 1];
    if (*flag == 1) {
        f32x2 o = {v0, v1};
        ((f32x2*)out)[(size_t)d * 16 + q] = o;
    } else {
        ((u32*)out)[(size_t)d * 16 + q] = (u32)f2bf(v0) | ((u32)f2bf(v1) << 16);
    }
}

extern "C" void kernel_launch(void* const* d_in, const int* in_sizes, int n_in,
                              void* d_out, int out_size, void* d_ws, size_t ws_size,
                              hipStream_t stream) {
    const void* features = d_in[0];
    const int* src = (const int*)d_in[1];
    const int* dst = (const int*)d_in[2];

    char* ws = (char*)d_ws;
    size_t off = 0;
    auto carve = [&](size_t bytes) -> void* {
        void* p = ws + off;
        off = (off + bytes + 255) & ~(size_t)255;
        return p;
    };
    int*   flags = (int*)carve(64);
    float* pconv = (float*)carve(2048 * 4);
    u16*   Wp0 = (u16*)carve(65536 * 2);
    u16*   Wp1 = (u16*)carve(65536 * 2);
    u16*   Wp2 = (u16*)carve(8192 * 2);
    u16*   Xb    = (u16*)carve((size_t)NN * 256 * 2);  // bf16 hidden state
    u16*   featb = (u16*)carve((size_t)NN * 256 * 2);  // bf16 GEMM output
    float* el   = (float*)carve((size_t)NN * 8 * 4);
    float* er   = (float*)carve((size_t)NN * 8 * 4);
    int*   deg     = (int*)carve((size_t)NN * 4);
    int*   cursor  = (int*)carve((size_t)NN * 4);
    int*   rowptr  = (int*)carve((size_t)(NN + 1) * 4);
    int*   bsum    = (int*)carve(256 * 4);
    int*   csr_src = (int*)carve((size_t)NE * 4);
    if (off > ws_size) return;  // clean ws-too-small signature

    const int N = NN, E = NE;
    const int nscan = (N + 255) / 256;   // 196 <= 256

    DetectArgs da;
    const int din_idx[13] = {0, 3, 4, 5, 6, 7, 8, 9, 10, 11, 12, 13, 14};
    for (int j = 0; j < 13; ++j) {
        da.p[j] = (const u32*)d_in[din_idx[j]];
        int nw = in_sizes[din_idx[j]] / 2;
        da.nw[j] = nw > 512 ? 512 : nw;
    }
    k_detect<<<1, 64, 0, stream>>>(da, flags);

    // 9 small params -> fp32
    ConvArgs ca;
    const int psl[9] = {4, 5, 6, 8, 9, 10, 12, 13, 14};
    const int pfl[9] = {2, 3, 4, 6, 7, 8, 10, 11, 12};
    float* dsts[9];
    {
        size_t o = 0;
        for (int j = 0; j < 9; ++j) {
            dsts[j] = pconv + o;
            o += (size_t)in_sizes[psl[j]];
        }
    }
    for (int j = 0; j < 9; ++j) {
        ca.s[j] = d_in[psl[j]];
        ca.d[j] = dsts[j];
        ca.n[j] = in_sizes[psl[j]];
        ca.fi[j] = pfl[j];
    }
    k_convert<<<dim3(1, 9), 256, 0, stream>>>(ca, flags);
    float* al0f = dsts[0]; float* ar0f = dsts[1]; float* b0f = dsts[2];
    float* al1f = dsts[3]; float* ar1f = dsts[4]; float* b1f = dsts[5];
    float* al2f = dsts[6]; float* ar2f = dsts[7]; float* b2f = dsts[8];

    // W packing into B-frag order (once)
    k_wpack<<<32, 256, 0, stream>>>(d_in[3],  flags, 1, 256, Wp0, 8192);
    k_wpack<<<32, 256, 0, stream>>>(d_in[7],  flags, 5, 256, Wp1, 8192);
    k_wpack<<<4,  256, 0, stream>>>(d_in[11], flags, 9, 32,  Wp2, 1024);

    // CSR build (multi-block scan)
    hipMemsetAsync(deg, 0, (size_t)N * 4, stream);
    k_hist<<<(E + 255) / 256, 256, 0, stream>>>(dst, deg, E);
    k_scan_partial<<<nscan, 256, 0, stream>>>(deg, bsum, N);
    k_scan_bsum<<<1, 256, 0, stream>>>(bsum, nscan);
    k_scan_final<<<nscan, 256, 0, stream>>>(deg, bsum, rowptr, cursor, N);
    k_scatter<<<(E + 255) / 256, 256, 0, stream>>>(src, dst, cursor, csr_src, E);

    const dim3 ggrid((N + 63) / 64, 2);

    // ---------------- layer 0 (reads features directly, dtype via flag) ----
    k_gemm_mfma<<<ggrid, 256, 0, stream>>>(features, flags, Wp0, featb, N);
    k_elr8<<<(N * 8 + 255) / 256, 256, 0, stream>>>(featb, al0f, ar0f, el, er, N);
    k_gather8<<<N / 8, 256, 0, stream>>>(rowptr, csr_src, el, er,
                                         (const u32v4*)featb, b0f, (u32v4*)Xb, E);

    // ---------------- layer 1 ----------------
    k_gemm_mfma<<<ggrid, 256, 0, stream>>>(Xb, nullptr, Wp1, featb, N);
    k_elr8<<<(N * 8 + 255) / 256, 256, 0, stream>>>(featb, al1f, ar1f, el, er, N);
    k_gather8<<<N / 8, 256, 0, stream>>>(rowptr, csr_src, el, er,
                                         (const u32v4*)featb, b1f, (u32v4*)Xb, E);

    // ---------------- layer 2 (1 head, D=32) ----------------
    k_gemm_mfma32<<<(N + 127) / 128, 256, 0, stream>>>(Xb, Wp2, featb, N);
    k_elr1<<<(N + 255) / 256, 256, 0, stream>>>(featb, al2f, ar2f, el, er, N);
    k_gather1<<<(N + 15) / 16, 256, 0, stream>>>(rowptr, csr_src, el, er,
                                                 (const u32*)featb, b2f,
                                                 d_out, flags, N);
}

// Round 13
// 449.190 us; speedup vs baseline: 1.1192x; 1.1192x over previous
//
#include <hip/hip_runtime.h>

typedef unsigned short u16;
typedef unsigned int   u32;
typedef __attribute__((ext_vector_type(8))) short  short8;
typedef __attribute__((ext_vector_type(4))) float  f32x4;
typedef __attribute__((ext_vector_type(2))) float  f32x2;
typedef __attribute__((ext_vector_type(2))) unsigned int u32v2;
typedef __attribute__((ext_vector_type(4))) unsigned int u32v4;

#define NN 50000
#define NE 800000

__device__ __forceinline__ float bf2f(u16 b) { return __uint_as_float(((u32)b) << 16); }
__device__ __forceinline__ float bflo(u32 p) { return __uint_as_float(p << 16); }
__device__ __forceinline__ float bfhi(u32 p) { return __uint_as_float(p & 0xffff0000u); }
__device__ __forceinline__ u16 f2bf(float f) {
    u32 u = __float_as_uint(f);
    u32 r = u + 0x7fffu + ((u >> 16) & 1u);
    return (u16)(r >> 16);
}
// leaky-relu + clamped exp (clamp is identity for this data's logit range)
__device__ __forceinline__ float lexp(float v) {
    v = v > 0.f ? v : 0.2f * v;
    return __expf(fminf(v, 60.f));
}

// ---------------------------------------------------------------------------
// dtype detection (parallel): flag 0=bf16, 1=fp32, 2=all-zero
// one block per tensor; 256 threads sample the same 512-word prefix
// ---------------------------------------------------------------------------
struct DetectArgs { const u32* p[13]; int nw[13]; };

__global__ __launch_bounds__(256) void k_detect(DetectArgs a, int* flags) {
    __shared__ int sh[256], sz[256];
    int j = blockIdx.x;
    const u32* x = a.p[j];
    int n = a.nw[j];
    int t = threadIdx.x;
    int hits = 0, nz = 0;
    for (int i = t; i < n; i += 256) {
        u32 w = x[i];
        if (w) {
            ++nz;
            u32 e = (w >> 7) & 0xffu;
            if (e >= 100 && e <= 150) ++hits;
        }
    }
    sh[t] = hits; sz[t] = nz;
    __syncthreads();
    for (int ofs = 128; ofs > 0; ofs >>= 1) {
        if (t < ofs) { sh[t] += sh[t + ofs]; sz[t] += sz[t + ofs]; }
        __syncthreads();
    }
    if (t == 0) flags[j] = (sz[0] == 0) ? 2 : ((sh[0] * 2 >= sz[0]) ? 0 : 1);
}

// convert ONLY the 9 small attention params (al/ar/b x 3 layers) to fp32.
struct ConvArgs { const void* s[9]; float* d[9]; int n[9]; int fi[9]; };

__global__ void k_convert(ConvArgs a, const int* __restrict__ flags) {
    int j = blockIdx.y;
    int i = blockIdx.x * 256 + threadIdx.x;
    if (i >= a.n[j]) return;
    int fl = flags[a.fi[j]];
    float v = 0.f;
    if (fl == 1) v = ((const float*)a.s[j])[i];
    else if (fl == 0) v = bf2f(((const u16*)a.s[j])[i]);
    a.d[j][i] = v;
}

// pack W[K=256][N] into MFMA B-fragment order:
// chunk id = (nt*8 + kt)*64 + L holds 8 bf16: W[kt*32 + (L>>4)*8 + j][nt*16 + (L&15)]
__global__ void k_wpack(const void* __restrict__ Wsrc, const int* __restrict__ flags,
                        int fidx, int N, u16* __restrict__ Wp, int nchunks) {
    int id = blockIdx.x * 256 + threadIdx.x;
    if (id >= nchunks) return;
    int L = id & 63, kt = (id >> 6) & 7, nt = id >> 9;
    int col = nt * 16 + (L & 15);
    int krow = kt * 32 + ((L >> 4) & 3) * 8;
    bool isf32 = (flags[fidx] == 1);
#pragma unroll
    for (int j = 0; j < 8; ++j) {
        int s = (krow + j) * N + col;
        Wp[id * 8 + j] = isf32 ? f2bf(((const float*)Wsrc)[s]) : ((const u16*)Wsrc)[s];
    }
}

// ---------------------------------------------------------------------------
// CSR build (graph static across layers) — 3-phase multi-block scan
// ---------------------------------------------------------------------------
__global__ void k_hist(const int* __restrict__ dst, int* __restrict__ deg, int E) {
    int e = blockIdx.x * 256 + threadIdx.x;
    if (e < E) atomicAdd(&deg[dst[e]], 1);
}

__global__ __launch_bounds__(256) void k_scan_partial(const int* __restrict__ deg,
                                                      int* __restrict__ bsum, int n) {
    __shared__ int red[256];
    int t = threadIdx.x;
    int i = blockIdx.x * 256 + t;
    red[t] = (i < n) ? deg[i] : 0;
    __syncthreads();
    for (int ofs = 128; ofs > 0; ofs >>= 1) {
        if (t < ofs) red[t] += red[t + ofs];
        __syncthreads();
    }
    if (t == 0) bsum[blockIdx.x] = red[0];
}

__global__ __launch_bounds__(256) void k_scan_bsum(int* __restrict__ bsum, int nb) {
    __shared__ int s[256];
    int t = threadIdx.x;
    int v = (t < nb) ? bsum[t] : 0;
    s[t] = v;
    __syncthreads();
    for (int ofs = 1; ofs < 256; ofs <<= 1) {
        int x = (t >= ofs) ? s[t - ofs] : 0;
        __syncthreads();
        s[t] += x;
        __syncthreads();
    }
    if (t < nb) bsum[t] = s[t] - v;   // exclusive
}

__global__ __launch_bounds__(256) void k_scan_final(const int* __restrict__ deg,
                                                    const int* __restrict__ bsum,
                                                    int* __restrict__ rowptr,
                                                    int* __restrict__ cursor, int n) {
    __shared__ int s[256];
    int t = threadIdx.x;
    int i = blockIdx.x * 256 + t;
    int v = (i < n) ? deg[i] : 0;
    s[t] = v;
    __syncthreads();
    for (int ofs = 1; ofs < 256; ofs <<= 1) {
        int x = (t >= ofs) ? s[t - ofs] : 0;
        __syncthreads();
        s[t] += x;
        __syncthreads();
    }
    int excl = bsum[blockIdx.x] + s[t] - v;
    if (i < n) {
        rowptr[i] = excl;
        cursor[i] = excl;
        if (i == n - 1) rowptr[n] = excl + v;
    }
}

__global__ void k_scatter(const int* __restrict__ src, const int* __restrict__ dst,
                          int* __restrict__ cursor, int* __restrict__ csr_src, int E) {
    int e = blockIdx.x * 256 + threadIdx.x;
    if (e >= E) return;
    int p = atomicAdd(&cursor[dst[e]], 1);
    csr_src[p] = src[e];
}

// ---------------------------------------------------------------------------
// MFMA GEMM: [nrows,256] x Wp(packed bf16) -> bf16 OUT [nrows,256]
// X read per runtime dtype flag (nullptr flag => bf16 buffer). fp32 path
// converts during LDS staging.
// ---------------------------------------------------------------------------
__global__ __launch_bounds__(256) void k_gemm_mfma(const void* __restrict__ Xv,
                                                   const int* __restrict__ xflag,
                                                   const u16* __restrict__ Wp,
                                                   u16* __restrict__ OUT, int nrows) {
    __shared__ u16 As[64 * 256];   // 32 KB
    const int t = threadIdx.x;
    const int w = t >> 6, L = t & 63;
    const int quad = (L >> 4) & 3;
    const int r0 = blockIdx.x * 64;
    const int nb = blockIdx.y * 8;
    const bool xf32 = (xflag != nullptr) && (*xflag == 1);

    short8* Asv = (short8*)As;
    short8 zero = {0, 0, 0, 0, 0, 0, 0, 0};
#pragma unroll
    for (int i = 0; i < 8; ++i) {
        int g = i * 256 + t;
        int row = g >> 5, cc = g & 31;
        int r = r0 + row;
        short8 val = zero;
        if (r < nrows) {
            if (xf32) {
                const f32x4* Xf4 = (const f32x4*)Xv;
                f32x4 lo = Xf4[(size_t)r * 64 + cc * 2];
                f32x4 hi = Xf4[(size_t)r * 64 + cc * 2 + 1];
                val[0] = (short)f2bf(lo[0]); val[1] = (short)f2bf(lo[1]);
                val[2] = (short)f2bf(lo[2]); val[3] = (short)f2bf(lo[3]);
                val[4] = (short)f2bf(hi[0]); val[5] = (short)f2bf(hi[1]);
                val[6] = (short)f2bf(hi[2]); val[7] = (short)f2bf(hi[3]);
            } else {
                val = ((const short8*)Xv)[(size_t)r * 32 + cc];
            }
        }
        Asv[cc * 64 + row] = val;
    }

    const short8* Wv = (const short8*)Wp;
    short8 bf[2][8];
#pragma unroll
    for (int jn = 0; jn < 2; ++jn) {
        int nt = nb + w + jn * 4;
#pragma unroll
        for (int kt = 0; kt < 8; ++kt) bf[jn][kt] = Wv[(nt * 8 + kt) * 64 + L];
    }
    __syncthreads();

    f32x4 acc[4][2];
#pragma unroll
    for (int mi = 0; mi < 4; ++mi)
#pragma unroll
        for (int jn = 0; jn < 2; ++jn) acc[mi][jn] = (f32x4){0.f, 0.f, 0.f, 0.f};

#pragma unroll
    for (int kt = 0; kt < 8; ++kt) {
#pragma unroll
        for (int mi = 0; mi < 4; ++mi) {
            short8 af = Asv[(kt * 4 + quad) * 64 + mi * 16 + (L & 15)];
            acc[mi][0] = __builtin_amdgcn_mfma_f32_16x16x32_bf16(af, bf[0][kt], acc[mi][0], 0, 0, 0);
            acc[mi][1] = __builtin_amdgcn_mfma_f32_16x16x32_bf16(af, bf[1][kt], acc[mi][1], 0, 0, 0);
        }
    }

    const int colbase = blockIdx.y * 128;
#pragma unroll
    for (int mi = 0; mi < 4; ++mi) {
        int rb = r0 + mi * 16 + quad * 4;
#pragma unroll
        for (int jn = 0; jn < 2; ++jn) {
            int c = colbase + (w + jn * 4) * 16 + (L & 15);
#pragma unroll
            for (int reg = 0; reg < 4; ++reg) {
                int r = rb + reg;
                if (r < nrows) OUT[(size_t)r * 256 + c] = f2bf(acc[mi][jn][reg]);
            }
        }
    }
}

// MFMA GEMM layer 2: [nrows,256](bf16) x Wp2 -> bf16 [nrows,32]. BM=128, BN=32.
__global__ __launch_bounds__(256) void k_gemm_mfma32(const u16* __restrict__ Xb,
                                                     const u16* __restrict__ Wp,
                                                     u16* __restrict__ OUT, int nrows) {
    __shared__ u16 As[128 * 256];  // 64 KB
    const int t = threadIdx.x;
    const int w = t >> 6, L = t & 63;
    const int quad = (L >> 4) & 3;
    const int r0 = blockIdx.x * 128;
    const int mh = (w >> 1) * 64, nt = w & 1;

    const short8* Xv = (const short8*)Xb;
    short8* Asv = (short8*)As;
    short8 zero = {0, 0, 0, 0, 0, 0, 0, 0};
#pragma unroll
    for (int i = 0; i < 16; ++i) {
        int g = i * 256 + t;
        int row = g >> 5, cc = g & 31;
        int r = r0 + row;
        Asv[cc * 128 + row] = (r < nrows) ? Xv[(size_t)r * 32 + cc] : zero;
    }

    const short8* Wv = (const short8*)Wp;
    short8 bf[8];
#pragma unroll
    for (int kt = 0; kt < 8; ++kt) bf[kt] = Wv[(nt * 8 + kt) * 64 + L];
    __syncthreads();

    f32x4 acc[4];
#pragma unroll
    for (int mi = 0; mi < 4; ++mi) acc[mi] = (f32x4){0.f, 0.f, 0.f, 0.f};

#pragma unroll
    for (int kt = 0; kt < 8; ++kt) {
#pragma unroll
        for (int mi = 0; mi < 4; ++mi) {
            short8 af = Asv[(kt * 4 + quad) * 128 + mh + mi * 16 + (L & 15)];
            acc[mi] = __builtin_amdgcn_mfma_f32_16x16x32_bf16(af, bf[kt], acc[mi], 0, 0, 0);
        }
    }

#pragma unroll
    for (int mi = 0; mi < 4; ++mi) {
        int rb = r0 + mh + mi * 16 + quad * 4;
        int c = nt * 16 + (L & 15);
#pragma unroll
        for (int reg = 0; reg < 4; ++reg) {
            int r = rb + reg;
            if (r < nrows) OUT[(size_t)r * 32 + c] = f2bf(acc[mi][reg]);
        }
    }
}

// attention logit dots (feat bf16, dwordx4 loads)
__global__ void k_elr8(const u16* __restrict__ featb, const float* __restrict__ al,
                       const float* __restrict__ ar, float* __restrict__ el,
                       float* __restrict__ er, int n) {
    int idx = blockIdx.x * 256 + threadIdx.x;
    if (idx >= n * 8) return;
    int node = idx >> 3, h = idx & 7;
    const u32v4* fu = (const u32v4*)((const u32*)featb + (size_t)node * 128 + h * 16);
    const float* A = al + h * 32;
    const float* B = ar + h * 32;
    float sl = 0.f, sr = 0.f;
#pragma unroll
    for (int j = 0; j < 4; ++j) {
        u32v4 w4 = fu[j];
#pragma unroll
        for (int k = 0; k < 4; ++k) {
            u32 w = (k == 0) ? w4.x : (k == 1) ? w4.y : (k == 2) ? w4.z : w4.w;
            float f0 = bflo(w), f1 = bfhi(w);
            int c = j * 8 + k * 2;
            sl += f0 * A[c] + f1 * A[c + 1];
            sr += f0 * B[c] + f1 * B[c + 1];
        }
    }
    el[idx] = sl;
    er[idx] = sr;
}

__global__ void k_elr1(const u16* __restrict__ featb, const float* __restrict__ al,
                       const float* __restrict__ ar, float* __restrict__ el,
                       float* __restrict__ er, int n) {
    int node = blockIdx.x * 256 + threadIdx.x;
    if (node >= n) return;
    const u32v4* fu = (const u32v4*)((const u32*)featb + (size_t)node * 16);
    float sl = 0.f, sr = 0.f;
#pragma unroll
    for (int j = 0; j < 4; ++j) {
        u32v4 w4 = fu[j];
#pragma unroll
        for (int k = 0; k < 4; ++k) {
            u32 w = (k == 0) ? w4.x : (k == 1) ? w4.y : (k == 2) ? w4.z : w4.w;
            float f0 = bflo(w), f1 = bfhi(w);
            int c = j * 8 + k * 2;
            sl += f0 * al[c] + f1 * al[c + 1];
            sr += f0 * ar[c] + f1 * ar[c + 1];
        }
    }
    el[node] = sl;
    er[node] = sr;
}

// ---------------------------------------------------------------------------
// fused softmax+gather: ONE WAVE PER NODE (64 lanes x dwordx2 = 4 cols/lane).
// (round-11 version — round-12's 2-nodes/wave predicated variant regressed:
//  wasted loads on predicated-off lanes +46MB FETCH, 69->80us)
// ---------------------------------------------------------------------------
__global__ __launch_bounds__(256) void k_gather8(const int* __restrict__ rowptr,
                                                 const int* __restrict__ csr_src,
                                                 const float* __restrict__ el,
                                                 const float* __restrict__ er,
                                                 const u32v2* __restrict__ featb4,
                                                 const float* __restrict__ bias,
                                                 u32v2* __restrict__ xout4) {
    int t = threadIdx.x;
    int d = blockIdx.x * 4 + (t >> 6);
    int q = t & 63;           // owns cols 4q..4q+3
    int h = q >> 3;           // head 0..7
    int b = rowptr[d], e = rowptr[d + 1];
    float erd = er[d * 8 + h];
    float a0 = 0.f, a1 = 0.f, a2 = 0.f, a3 = 0.f, ssum = 0.f;
    int p = b;
    for (; p + 4 <= e; p += 4) {
        int s0 = csr_src[p], s1 = csr_src[p + 1], s2 = csr_src[p + 2], s3 = csr_src[p + 3];
        float e0 = lexp(el[s0 * 8 + h] + erd);
        float e1 = lexp(el[s1 * 8 + h] + erd);
        float e2 = lexp(el[s2 * 8 + h] + erd);
        float e3 = lexp(el[s3 * 8 + h] + erd);
        u32v2 w0 = featb4[(size_t)s0 * 64 + q];
        u32v2 w1 = featb4[(size_t)s1 * 64 + q];
        u32v2 w2 = featb4[(size_t)s2 * 64 + q];
        u32v2 w3 = featb4[(size_t)s3 * 64 + q];
        a0 += bflo(w0.x) * e0; a1 += bfhi(w0.x) * e0; a2 += bflo(w0.y) * e0; a3 += bfhi(w0.y) * e0;
        a0 += bflo(w1.x) * e1; a1 += bfhi(w1.x) * e1; a2 += bflo(w1.y) * e1; a3 += bfhi(w1.y) * e1;
        a0 += bflo(w2.x) * e2; a1 += bfhi(w2.x) * e2; a2 += bflo(w2.y) * e2; a3 += bfhi(w2.y) * e2;
        a0 += bflo(w3.x) * e3; a1 += bfhi(w3.x) * e3; a2 += bflo(w3.y) * e3; a3 += bfhi(w3.y) * e3;
        ssum += (e0 + e1) + (e2 + e3);
    }
    for (; p < e; ++p) {
        int s = csr_src[p];
        float ev = lexp(el[s * 8 + h] + erd);
        u32v2 w = featb4[(size_t)s * 64 + q];
        a0 += bflo(w.x) * ev; a1 += bfhi(w.x) * ev;
        a2 += bflo(w.y) * ev; a3 += bfhi(w.y) * ev;
        ssum += ev;
    }
    float rd = 1.f / (ssum + 1e-9f);
    const float4 bb = *(const float4*)&bias[4 * q];
    float v0 = a0 * rd + bb.x;
    float v1 = a1 * rd + bb.y;
    float v2 = a2 * rd + bb.z;
    float v3 = a3 * rd + bb.w;
    v0 = v0 > 0.f ? v0 : expm1f(v0);
    v1 = v1 > 0.f ? v1 : expm1f(v1);
    v2 = v2 > 0.f ? v2 : expm1f(v2);
    v3 = v3 > 0.f ? v3 : expm1f(v3);
    u32v2 o;
    o.x = (u32)f2bf(v0) | ((u32)f2bf(v1) << 16);
    o.y = (u32)f2bf(v2) | ((u32)f2bf(v3) << 16);
    xout4[(size_t)d * 64 + q] = o;
}

// layer-2 fused gather: 16 lanes/node x u32 (2 cols/lane), 4 nodes/wave.
__global__ __launch_bounds__(256) void k_gather1(const int* __restrict__ rowptr,
                                                 const int* __restrict__ csr_src,
                                                 const float* __restrict__ el,
                                                 const float* __restrict__ er,
                                                 const u32* __restrict__ featb2,
                                                 const float* __restrict__ bias,
                                                 void* __restrict__ out,
                                                 const int* __restrict__ flag, int n) {
    int t = threadIdx.x;
    int d = blockIdx.x * 16 + (t >> 4);
    int q = t & 15;           // owns cols 2q, 2q+1
    if (d >= n) return;
    int b = rowptr[d], e = rowptr[d + 1];
    float erd = er[d];
    float a0 = 0.f, a1 = 0.f, ssum = 0.f;
    int p = b;
    for (; p + 4 <= e; p += 4) {
        int s0 = csr_src[p], s1 = csr_src[p + 1], s2 = csr_src[p + 2], s3 = csr_src[p + 3];
        float e0 = lexp(el[s0] + erd);
        float e1 = lexp(el[s1] + erd);
        float e2 = lexp(el[s2] + erd);
        float e3 = lexp(el[s3] + erd);
        u32 w0 = featb2[(size_t)s0 * 16 + q];
        u32 w1 = featb2[(size_t)s1 * 16 + q];
        u32 w2 = featb2[(size_t)s2 * 16 + q];
        u32 w3 = featb2[(size_t)s3 * 16 + q];
        a0 += bflo(w0) * e0; a1 += bfhi(w0) * e0;
        a0 += bflo(w1) * e1; a1 += bfhi(w1) * e1;
        a0 += bflo(w2) * e2; a1 += bfhi(w2) * e2;
        a0 += bflo(w3) * e3; a1 += bfhi(w3) * e3;
        ssum += (e0 + e1) + (e2 + e3);
    }
    for (; p < e; ++p) {
        int s = csr_src[p];
        float ev = lexp(el[s] + erd);
        u32 w = featb2[(size_t)s * 16 + q];
        a0 += bflo(w) * ev;
        a1 += bfhi(w) * ev;
        ssum += ev;
    }
    float rd = 1.f / (ssum + 1e-9f);
    float v0 = a0 * rd + bias[2 * q];
    float v1 = a1 * rd + bias[2 * q + 1];
    if (*flag == 1) {
        f32x2 o = {v0, v1};
        ((f32x2*)out)[(size_t)d * 16 + q] = o;
    } else {
        ((u32*)out)[(size_t)d * 16 + q] = (u32)f2bf(v0) | ((u32)f2bf(v1) << 16);
    }
}

extern "C" void kernel_launch(void* const* d_in, const int* in_sizes, int n_in,
                              void* d_out, int out_size, void* d_ws, size_t ws_size,
                              hipStream_t stream) {
    const void* features = d_in[0];
    const int* src = (const int*)d_in[1];
    const int* dst = (const int*)d_in[2];

    char* ws = (char*)d_ws;
    size_t off = 0;
    auto carve = [&](size_t bytes) -> void* {
        void* p = ws + off;
        off = (off + bytes + 255) & ~(size_t)255;
        return p;
    };
    int*   flags = (int*)carve(64);
    float* pconv = (float*)carve(2048 * 4);
    u16*   Wp0 = (u16*)carve(65536 * 2);
    u16*   Wp1 = (u16*)carve(65536 * 2);
    u16*   Wp2 = (u16*)carve(8192 * 2);
    u16*   Xb    = (u16*)carve((size_t)NN * 256 * 2);  // bf16 hidden state
    u16*   featb = (u16*)carve((size_t)NN * 256 * 2);  // bf16 GEMM output
    float* el   = (float*)carve((size_t)NN * 8 * 4);
    float* er   = (float*)carve((size_t)NN * 8 * 4);
    int*   deg     = (int*)carve((size_t)NN * 4);
    int*   cursor  = (int*)carve((size_t)NN * 4);
    int*   rowptr  = (int*)carve((size_t)(NN + 1) * 4);
    int*   bsum    = (int*)carve(256 * 4);
    int*   csr_src = (int*)carve((size_t)NE * 4);
    if (off > ws_size) return;  // clean ws-too-small signature

    const int N = NN, E = NE;
    const int nscan = (N + 255) / 256;   // 196 <= 256

    DetectArgs da;
    const int din_idx[13] = {0, 3, 4, 5, 6, 7, 8, 9, 10, 11, 12, 13, 14};
    for (int j = 0; j < 13; ++j) {
        da.p[j] = (const u32*)d_in[din_idx[j]];
        int nw = in_sizes[din_idx[j]] / 2;
        da.nw[j] = nw > 512 ? 512 : nw;
    }
    k_detect<<<13, 256, 0, stream>>>(da, flags);

    // 9 small params -> fp32
    ConvArgs ca;
    const int psl[9] = {4, 5, 6, 8, 9, 10, 12, 13, 14};
    const int pfl[9] = {2, 3, 4, 6, 7, 8, 10, 11, 12};
    float* dsts[9];
    {
        size_t o = 0;
        for (int j = 0; j < 9; ++j) {
            dsts[j] = pconv + o;
            o += (size_t)in_sizes[psl[j]];
        }
    }
    for (int j = 0; j < 9; ++j) {
        ca.s[j] = d_in[psl[j]];
        ca.d[j] = dsts[j];
        ca.n[j] = in_sizes[psl[j]];
        ca.fi[j] = pfl[j];
    }
    k_convert<<<dim3(1, 9), 256, 0, stream>>>(ca, flags);
    float* al0f = dsts[0]; float* ar0f = dsts[1]; float* b0f = dsts[2];
    float* al1f = dsts[3]; float* ar1f = dsts[4]; float* b1f = dsts[5];
    float* al2f = dsts[6]; float* ar2f = dsts[7]; float* b2f = dsts[8];

    // W packing into B-frag order (once)
    k_wpack<<<32, 256, 0, stream>>>(d_in[3],  flags, 1, 256, Wp0, 8192);
    k_wpack<<<32, 256, 0, stream>>>(d_in[7],  flags, 5, 256, Wp1, 8192);
    k_wpack<<<4,  256, 0, stream>>>(d_in[11], flags, 9, 32,  Wp2, 1024);

    // CSR build (multi-block scan)
    hipMemsetAsync(deg, 0, (size_t)N * 4, stream);
    k_hist<<<(E + 255) / 256, 256, 0, stream>>>(dst, deg, E);
    k_scan_partial<<<nscan, 256, 0, stream>>>(deg, bsum, N);
    k_scan_bsum<<<1, 256, 0, stream>>>(bsum, nscan);
    k_scan_final<<<nscan, 256, 0, stream>>>(deg, bsum, rowptr, cursor, N);
    k_scatter<<<(E + 255) / 256, 256, 0, stream>>>(src, dst, cursor, csr_src, E);

    const dim3 ggrid((N + 63) / 64, 2);

    // ---------------- layer 0 (reads features directly, dtype via flag) ----
    k_gemm_mfma<<<ggrid, 256, 0, stream>>>(features, flags, Wp0, featb, N);
    k_elr8<<<(N * 8 + 255) / 256, 256, 0, stream>>>(featb, al0f, ar0f, el, er, N);
    k_gather8<<<N / 4, 256, 0, stream>>>(rowptr, csr_src, el, er,
                                         (const u32v2*)featb, b0f, (u32v2*)Xb);

    // ---------------- layer 1 ----------------
    k_gemm_mfma<<<ggrid, 256, 0, stream>>>(Xb, nullptr, Wp1, featb, N);
    k_elr8<<<(N * 8 + 255) / 256, 256, 0, stream>>>(featb, al1f, ar1f, el, er, N);
    k_gather8<<<N / 4, 256, 0, stream>>>(rowptr, csr_src, el, er,
                                         (const u32v2*)featb, b1f, (u32v2*)Xb);

    // ---------------- layer 2 (1 head, D=32) ----------------
    k_gemm_mfma32<<<(N + 127) / 128, 256, 0, stream>>>(Xb, Wp2, featb, N);
    k_elr1<<<(N + 255) / 256, 256, 0, stream>>>(featb, al2f, ar2f, el, er, N);
    k_gather1<<<(N + 15) / 16, 256, 0, stream>>>(rowptr, csr_src, el, er,
                                                 (const u32*)featb, b2f,
                                                 d_out, flags, N);
}